// Round 2
// baseline (223.423 us; speedup 1.0000x reference)
//
#include <hip/hip_runtime.h>

#define B_ 2048
#define T_ 500
#define N_ 64
#define BT (B_ * T_)

// ---------------------------------------------------------------------------
// Kernel 1: row sums.  S[r] = sum_n input[r*64 + n],  r = b*T + t.
// One thread per float4 chunk (16 chunks per row -> 16 lanes cooperate per
// row), fully coalesced: each wave reads 1 KB contiguous per instruction.
// At the HBM roofline (262 MB / ~6.3 TB/s ≈ 42 µs).
// ---------------------------------------------------------------------------
__global__ __launch_bounds__(256) void rowsum_kernel(const float* __restrict__ in,
                                                     float* __restrict__ S) {
    long long gid = (long long)blockIdx.x * 256 + threadIdx.x;  // chunk index
    const float4* p = (const float4*)in;
    float4 v = p[gid];
    float s = (v.x + v.y) + (v.z + v.w);
    s += __shfl_xor(s, 1);
    s += __shfl_xor(s, 2);
    s += __shfl_xor(s, 4);
    s += __shfl_xor(s, 8);
    if ((threadIdx.x & 15) == 0) S[gid >> 4] = s;
}

// ---------------------------------------------------------------------------
// Izhikevich Euler step, matching the reference's association order exactly.
// DT = 0.25; all neuron types have a = 0.02 -> DT*a = 0.005f.
// ---------------------------------------------------------------------------
__device__ __forceinline__ float izh(float& v, float& u, float I,
                                     float b, float c, float d) {
    float t  = 0.04f * v * v + 5.0f * v + 140.0f - u + I;
    float v_ = v + 0.25f * t;
    float u_ = u + 0.005f * (b * v - u);
    float z  = (v_ >= 30.0f) ? 1.0f : 0.0f;
    v = (v_ >= 30.0f) ? c : v_;
    u = u_ + z * d;
    return z;
}

// ---------------------------------------------------------------------------
// Kernel 2: the sequential scan. One thread per batch element; the two
// channels are independent dependency chains -> ILP. Latency-bound by design.
// Templated on SPtr so the no-alias (restrict) variant is used whenever S
// lives in the workspace: without restrict the compiler must assume the
// Srow loads alias the out stores and inserts s_waitcnt vmcnt drains of the
// (uncoalesced) store queue on the critical path.
// ---------------------------------------------------------------------------
template <typename SPtr, typename OPtr>
__device__ __forceinline__ void scan_body(SPtr S, const float* __restrict__ w24,
                                          OPtr out) {
    int b = blockIdx.x * 64 + threadIdx.x;
    if (b >= B_) return;

    const float w0 = w24[0],  w1 = w24[1],  w2 = w24[2],  w3 = w24[3];
    const float w4 = w24[4],  w5 = w24[5],  w6 = w24[6];
    const float w8 = w24[8],  w9 = w24[9],  w10 = w24[10], w11 = w24[11];
    const float w12 = w24[12], w13 = w24[13], w16 = w24[16], w17 = w24[17];
    const float w18 = w24[18], w20 = w24[20], w23 = w24[23];

    float vL = -70.f, uL = -14.f, zL = 0.f;
    float vE = -64.f, uE = -16.f;
    float vI = -64.f, uI = -16.f;
    float vT = -70.f, uT = -14.f, zT = 0.f;
    float vM = -64.f, uM = -16.f;
    float vL2 = -70.f, uL2 = -14.f, zL2 = 0.f;
    float vE2 = -64.f, uE2 = -16.f;
    float vI2 = -64.f, uI2 = -16.f;
    float vT2 = -70.f, uT2 = -14.f, zT2 = 0.f;
    float vM2 = -64.f, uM2 = -16.f;

    const float4* Srow = (const float4*)(&S[(size_t)b * T_]);
    float4* q0 = (float4*)(&out[(size_t)b * T_]);                  // o_spikes
    float4* q1 = (float4*)(&out[(size_t)BT + (size_t)b * T_]);     // v
    float4* q2 = (float4*)(&out[(size_t)2 * BT + (size_t)b * T_]); // o_spikes2
    float4* q3 = (float4*)(&out[(size_t)3 * BT + (size_t)b * T_]); // v2
    float4* p4 = (float4*)(&out[(size_t)4 * BT]) + (size_t)b * T_; // o_spikes_o
    float4* p5 = (float4*)(&out[(size_t)8 * BT]) + (size_t)b * T_; // v_o

    // S prefetch pipeline, 2 iterations (8 steps) deep.
    float4 sc = Srow[0];
    float4 sn = Srow[1];
    for (int i = 0; i < T_ / 4; ++i) {
        float4 sn2 = sn;
        if (i + 2 < T_ / 4) sn2 = Srow[i + 2];
        float sv[4] = {sc.x, sc.y, sc.z, sc.w};
        float o0[4], o1[4], o2[4], o3[4];
#pragma unroll
        for (int k = 0; k < 4; ++k) {
            int t = 4 * i + k;
            float Ssum = sv[k];
            float zp  = Ssum * w0;
            float zp2 = Ssum * w12;
            // --- channel 1 ---
            float z2 = izh(vL, uL, w2 * (zp * w1) + w3 * zL, 0.20f, -65.f, 6.f);
            float z3 = izh(vE, uE, zp * w4 + z2 * w5,        0.25f, -55.f, 0.05f);
            float z4 = izh(vI, uI, z3 * w6,                  0.25f, -65.f, 6.f);
            float z5 = izh(vT, uT, w9 * (z3 * w8) + w10 * zT,0.20f, -50.f, 2.f);
            float z6 = izh(vM, uM, z5 * w11,                 0.25f, -65.f, 6.f);
            zL = z2; zT = z5;
            // --- channel 2 ---
            float z22 = izh(vL2, uL2, w2 * (zp2 * w13) + w3 * zL2, 0.20f, -65.f, 6.f);
            float z32 = izh(vE2, uE2, zp2 * w16 + z22 * w17,       0.25f, -55.f, 0.05f);
            float z42 = izh(vI2, uI2, z32 * w18,                   0.25f, -65.f, 6.f);
            float z52 = izh(vT2, uT2, w9 * (z32 * w20) + w10 * zT2,0.20f, -50.f, 2.f);
            float z62 = izh(vM2, uM2, z52 * w23,                   0.25f, -65.f, 6.f);
            zL2 = z22; zT2 = z52;
            (void)z42;

            o0[k] = z6;  o1[k] = vM;  o2[k] = z62;  o3[k] = vM2;
            p4[t] = make_float4(z2, z3, z4, z5);
            p5[t] = make_float4(vL, vE, vI, vT);
        }
        q0[i] = make_float4(o0[0], o0[1], o0[2], o0[3]);
        q1[i] = make_float4(o1[0], o1[1], o1[2], o1[3]);
        q2[i] = make_float4(o2[0], o2[1], o2[2], o2[3]);
        q3[i] = make_float4(o3[0], o3[1], o3[2], o3[3]);
        sc = sn;
        sn = sn2;
    }
}

__global__ __launch_bounds__(64) void scan_kernel_ws(const float* __restrict__ S,
                                                     const float* __restrict__ w24,
                                                     float* __restrict__ out) {
    scan_body(S, w24, out);
}

// Fallback when ws is too small: S aliases out's o_spikes region (per-thread
// reads strictly lead writes there); no restrict so ordering is preserved.
__global__ __launch_bounds__(64) void scan_kernel_alias(const float* S,
                                                        const float* __restrict__ w24,
                                                        float* out) {
    scan_body(S, w24, out);
}

extern "C" void kernel_launch(void* const* d_in, const int* in_sizes, int n_in,
                              void* d_out, int out_size, void* d_ws, size_t ws_size,
                              hipStream_t stream) {
    const float* in = (const float*)d_in[0];
    const float* w  = (const float*)d_in[1];
    float* out = (float*)d_out;

    bool use_ws = ws_size >= (size_t)BT * sizeof(float);
    float* S = use_ws ? (float*)d_ws : out;

    rowsum_kernel<<<(BT * 16) / 256, 256, 0, stream>>>(in, S);

    if (use_ws) {
        scan_kernel_ws<<<(B_ + 63) / 64, 64, 0, stream>>>(S, w, out);
    } else {
        scan_kernel_alias<<<(B_ + 63) / 64, 64, 0, stream>>>(S, w, out);
    }
}

// Round 3
// 221.492 us; speedup vs baseline: 1.0087x; 1.0087x over previous
//
#include <hip/hip_runtime.h>

#define B_ 2048
#define T_ 500
#define N_ 64
#define BT (B_ * T_)
#define TILE 32

// ---------------------------------------------------------------------------
// Kernel 1: row sums.  S[r] = sum_n input[r*64 + n],  r = b*T + t.
// 16 lanes cooperate per row; fully coalesced 1 KB/wave loads. HBM roofline.
// ---------------------------------------------------------------------------
__global__ __launch_bounds__(256) void rowsum_kernel(const float* __restrict__ in,
                                                     float* __restrict__ S) {
    long long gid = (long long)blockIdx.x * 256 + threadIdx.x;  // chunk index
    const float4* p = (const float4*)in;
    float4 v = p[gid];
    float s = (v.x + v.y) + (v.z + v.w);
    s += __shfl_xor(s, 1);
    s += __shfl_xor(s, 2);
    s += __shfl_xor(s, 4);
    s += __shfl_xor(s, 8);
    if ((threadIdx.x & 15) == 0) S[gid >> 4] = s;
}

// ---------------------------------------------------------------------------
// Izhikevich Euler step, matching the reference's association order exactly.
// DT = 0.25; all neuron types have a = 0.02 -> DT*a = 0.005f.
// ---------------------------------------------------------------------------
__device__ __forceinline__ float izh(float& v, float& u, float I,
                                     float b, float c, float d) {
    float t  = 0.04f * v * v + 5.0f * v + 140.0f - u + I;
    float v_ = v + 0.25f * t;
    float u_ = u + 0.005f * (b * v - u);
    float z  = (v_ >= 30.0f) ? 1.0f : 0.0f;
    v = (v_ >= 30.0f) ? c : v_;
    u = u_ + z * d;
    return z;
}

// ---------------------------------------------------------------------------
// Kernel 2 (main path): scan with LDS tile-transpose so ALL global stores are
// coalesced. Block = 64 threads = 64 batch rows; outputs staged per 32-step
// tile in [b][t] LDS layout, then dumped with consecutive lanes -> consecutive
// addresses. S is preloaded one tile ahead into registers.
// ---------------------------------------------------------------------------
__global__ __launch_bounds__(64) void scan_lds_kernel(const float* __restrict__ S,
                                                      const float* __restrict__ w24,
                                                      float* __restrict__ out) {
    __shared__ float l0[64][36];   // z6   (o_spikes)   rows 144B (16B-mult)
    __shared__ float l1[64][36];   // vM   (v)
    __shared__ float l2[64][36];   // z62  (o_spikes2)
    __shared__ float l3[64][36];   // vM2  (v2)
    __shared__ float l4[64][132];  // o_spikes_o [b][t*4+c], rows 528B
    __shared__ float l5[64][132];  // v_o

    const int lane = threadIdx.x;
    const int b = blockIdx.x * 64 + lane;

    const float w0 = w24[0],  w1 = w24[1],  w2 = w24[2],  w3 = w24[3];
    const float w4 = w24[4],  w5 = w24[5],  w6 = w24[6];
    const float w8 = w24[8],  w9 = w24[9],  w10 = w24[10], w11 = w24[11];
    const float w12 = w24[12], w13 = w24[13], w16 = w24[16], w17 = w24[17];
    const float w18 = w24[18], w20 = w24[20], w23 = w24[23];

    float vL = -70.f, uL = -14.f, zL = 0.f;
    float vE = -64.f, uE = -16.f;
    float vI = -64.f, uI = -16.f;
    float vT = -70.f, uT = -14.f, zT = 0.f;
    float vM = -64.f, uM = -16.f;
    float vL2 = -70.f, uL2 = -14.f, zL2 = 0.f;
    float vE2 = -64.f, uE2 = -16.f;
    float vI2 = -64.f, uI2 = -16.f;
    float vT2 = -70.f, uT2 = -14.f, zT2 = 0.f;
    float vM2 = -64.f, uM2 = -16.f;

    const float4* S4 = (const float4*)(S + (size_t)b * T_);  // 125 float4/row
    const size_t brow = (size_t)blockIdx.x * 64;

    float4 cur[8], nxt[8];
#pragma unroll
    for (int f = 0; f < 8; ++f) cur[f] = S4[f];

    const int ntiles = (T_ + TILE - 1) / TILE;  // 16 (15 full + one 20-step)
    for (int ti = 0; ti < ntiles; ++ti) {
        const int t0 = ti * TILE;
        const int nt = (T_ - t0 < TILE) ? (T_ - t0) : TILE;

        // Prefetch next tile's S (latency hides under compute + dump).
        if (ti + 1 < ntiles) {
            const int base = (t0 + TILE) >> 2;
            const int nf = ((T_ - t0 - TILE < TILE ? T_ - t0 - TILE : TILE) + 3) >> 2;
#pragma unroll
            for (int f = 0; f < 8; ++f)
                if (f < nf) nxt[f] = S4[base + f];
        }

        // ---- produce nt steps into LDS ----
#pragma unroll
        for (int q = 0; q < 8; ++q) {
            if (4 * q >= nt) continue;
            float sv[4] = {cur[q].x, cur[q].y, cur[q].z, cur[q].w};
#pragma unroll
            for (int k = 0; k < 4; ++k) {
                const int tt = 4 * q + k;
                float Ssum = sv[k];
                float zp  = Ssum * w0;
                float zp2 = Ssum * w12;
                // --- channel 1 ---
                float z2 = izh(vL, uL, w2 * (zp * w1) + w3 * zL, 0.20f, -65.f, 6.f);
                float z3 = izh(vE, uE, zp * w4 + z2 * w5,        0.25f, -55.f, 0.05f);
                float z4 = izh(vI, uI, z3 * w6,                  0.25f, -65.f, 6.f);
                float z5 = izh(vT, uT, w9 * (z3 * w8) + w10 * zT,0.20f, -50.f, 2.f);
                float z6 = izh(vM, uM, z5 * w11,                 0.25f, -65.f, 6.f);
                zL = z2; zT = z5;
                // --- channel 2 ---
                float z22 = izh(vL2, uL2, w2 * (zp2 * w13) + w3 * zL2, 0.20f, -65.f, 6.f);
                float z32 = izh(vE2, uE2, zp2 * w16 + z22 * w17,       0.25f, -55.f, 0.05f);
                float z42 = izh(vI2, uI2, z32 * w18,                   0.25f, -65.f, 6.f);
                float z52 = izh(vT2, uT2, w9 * (z32 * w20) + w10 * zT2,0.20f, -50.f, 2.f);
                float z62 = izh(vM2, uM2, z52 * w23,                   0.25f, -65.f, 6.f);
                zL2 = z22; zT2 = z52;
                (void)z42;

                l0[lane][tt] = z6;
                l1[lane][tt] = vM;
                l2[lane][tt] = z62;
                l3[lane][tt] = vM2;
                *(float4*)&l4[lane][tt * 4] = make_float4(z2, z3, z4, z5);
                *(float4*)&l5[lane][tt * 4] = make_float4(vL, vE, vI, vT);
            }
        }
        __syncthreads();

        // ---- dump tile, coalesced ----
        const int nf4 = nt >> 2;  // float4 per scalar row (8 or 5)
        {
            // scalar streams: lane k -> row 8j+(k>>3), float4 f=k&7
            const int r = lane >> 3, f = lane & 7;
#pragma unroll
            for (int j = 0; j < 8; ++j) {
                const int row = j * 8 + r;
                if (f < nf4) {
                    const size_t g = (brow + row) * T_ + t0 + f * 4;
                    *(float4*)&out[g]                    = *(const float4*)&l0[row][f * 4];
                    *(float4*)&out[(size_t)BT + g]       = *(const float4*)&l1[row][f * 4];
                    *(float4*)&out[(size_t)2 * BT + g]   = *(const float4*)&l2[row][f * 4];
                    *(float4*)&out[(size_t)3 * BT + g]   = *(const float4*)&l3[row][f * 4];
                }
            }
        }
        {
            // x4 streams: lane k -> row 2j+(k>>5), t-offset tt=k&31
            const int r = lane >> 5, tt = lane & 31;
            float4* o4 = (float4*)out;
#pragma unroll
            for (int j = 0; j < 32; ++j) {
                const int row = 2 * j + r;
                if (tt < nt) {
                    const size_t g = (brow + row) * T_ + t0 + tt;  // float4 index
                    o4[(size_t)BT + g]     = *(const float4*)&l4[row][tt * 4];  // o_spikes_o
                    o4[(size_t)2 * BT + g] = *(const float4*)&l5[row][tt * 4];  // v_o
                }
            }
        }
        __syncthreads();

#pragma unroll
        for (int f = 0; f < 8; ++f) cur[f] = nxt[f];
    }
}

// ---------------------------------------------------------------------------
// Fallback (tiny ws): round-1 scattered-store scan, S aliasing out's o_spikes
// region (per-thread reads strictly lead writes; no restrict -> order kept).
// ---------------------------------------------------------------------------
__global__ __launch_bounds__(64) void scan_kernel_alias(const float* S,
                                                        const float* __restrict__ w24,
                                                        float* out) {
    int b = blockIdx.x * 64 + threadIdx.x;
    if (b >= B_) return;

    const float w0 = w24[0],  w1 = w24[1],  w2 = w24[2],  w3 = w24[3];
    const float w4 = w24[4],  w5 = w24[5],  w6 = w24[6];
    const float w8 = w24[8],  w9 = w24[9],  w10 = w24[10], w11 = w24[11];
    const float w12 = w24[12], w13 = w24[13], w16 = w24[16], w17 = w24[17];
    const float w18 = w24[18], w20 = w24[20], w23 = w24[23];

    float vL = -70.f, uL = -14.f, zL = 0.f;
    float vE = -64.f, uE = -16.f;
    float vI = -64.f, uI = -16.f;
    float vT = -70.f, uT = -14.f, zT = 0.f;
    float vM = -64.f, uM = -16.f;
    float vL2 = -70.f, uL2 = -14.f, zL2 = 0.f;
    float vE2 = -64.f, uE2 = -16.f;
    float vI2 = -64.f, uI2 = -16.f;
    float vT2 = -70.f, uT2 = -14.f, zT2 = 0.f;
    float vM2 = -64.f, uM2 = -16.f;

    const float4* Srow = (const float4*)(S + (size_t)b * T_);
    float* p0 = out + (size_t)b * T_;
    float* p1 = p0 + (size_t)BT;
    float* p2 = p0 + (size_t)2 * BT;
    float* p3 = p0 + (size_t)3 * BT;
    float4* p4 = (float4*)out + (size_t)BT + (size_t)b * T_;
    float4* p5 = (float4*)out + (size_t)2 * BT + (size_t)b * T_;

    float4 sc = Srow[0];
    for (int i = 0; i < T_ / 4; ++i) {
        float4 sn = sc;
        if (i + 1 < T_ / 4) sn = Srow[i + 1];
        float sv[4] = {sc.x, sc.y, sc.z, sc.w};
#pragma unroll
        for (int k = 0; k < 4; ++k) {
            int t = 4 * i + k;
            float Ssum = sv[k];
            float zp  = Ssum * w0;
            float zp2 = Ssum * w12;
            float z2 = izh(vL, uL, w2 * (zp * w1) + w3 * zL, 0.20f, -65.f, 6.f);
            float z3 = izh(vE, uE, zp * w4 + z2 * w5,        0.25f, -55.f, 0.05f);
            float z4 = izh(vI, uI, z3 * w6,                  0.25f, -65.f, 6.f);
            float z5 = izh(vT, uT, w9 * (z3 * w8) + w10 * zT,0.20f, -50.f, 2.f);
            float z6 = izh(vM, uM, z5 * w11,                 0.25f, -65.f, 6.f);
            zL = z2; zT = z5;
            float z22 = izh(vL2, uL2, w2 * (zp2 * w13) + w3 * zL2, 0.20f, -65.f, 6.f);
            float z32 = izh(vE2, uE2, zp2 * w16 + z22 * w17,       0.25f, -55.f, 0.05f);
            float z42 = izh(vI2, uI2, z32 * w18,                   0.25f, -65.f, 6.f);
            float z52 = izh(vT2, uT2, w9 * (z32 * w20) + w10 * zT2,0.20f, -50.f, 2.f);
            float z62 = izh(vM2, uM2, z52 * w23,                   0.25f, -65.f, 6.f);
            zL2 = z22; zT2 = z52;
            (void)z42;

            p0[t] = z6;
            p1[t] = vM;
            p2[t] = z62;
            p3[t] = vM2;
            p4[t] = make_float4(z2, z3, z4, z5);
            p5[t] = make_float4(vL, vE, vI, vT);
        }
        sc = sn;
    }
}

extern "C" void kernel_launch(void* const* d_in, const int* in_sizes, int n_in,
                              void* d_out, int out_size, void* d_ws, size_t ws_size,
                              hipStream_t stream) {
    const float* in = (const float*)d_in[0];
    const float* w  = (const float*)d_in[1];
    float* out = (float*)d_out;

    bool use_ws = ws_size >= (size_t)BT * sizeof(float);
    float* S = use_ws ? (float*)d_ws : out;

    rowsum_kernel<<<(BT * 16) / 256, 256, 0, stream>>>(in, S);

    if (use_ws) {
        scan_lds_kernel<<<B_ / 64, 64, 0, stream>>>(S, w, out);
    } else {
        scan_kernel_alias<<<(B_ + 63) / 64, 64, 0, stream>>>(S, w, out);
    }
}

// Round 4
// 177.978 us; speedup vs baseline: 1.2553x; 1.2445x over previous
//
#include <hip/hip_runtime.h>

#define B_ 2048
#define T_ 500
#define N_ 64
#define BT (B_ * T_)

// ---------------------------------------------------------------------------
// Kernel 1: row sums.  S[r] = sum_n input[r*64 + n],  r = b*T + t.
// 16 lanes cooperate per row; fully coalesced 1 KB/wave loads. ~92% of
// achievable HBM BW already (262 MB in ~45 us).
// ---------------------------------------------------------------------------
__global__ __launch_bounds__(256) void rowsum_kernel(const float* __restrict__ in,
                                                     float* __restrict__ S) {
    long long gid = (long long)blockIdx.x * 256 + threadIdx.x;  // chunk index
    const float4* p = (const float4*)in;
    float4 v = p[gid];
    float s = (v.x + v.y) + (v.z + v.w);
    s += __shfl_xor(s, 1);
    s += __shfl_xor(s, 2);
    s += __shfl_xor(s, 4);
    s += __shfl_xor(s, 8);
    if ((threadIdx.x & 15) == 0) S[gid >> 4] = s;
}

// ---------------------------------------------------------------------------
// Izhikevich Euler step — association order matches the reference exactly.
// DT = 0.25; all neuron types have a = 0.02 -> DT*a = 0.005f.
// ---------------------------------------------------------------------------
__device__ __forceinline__ float izh(float& v, float& u, float I,
                                     float b, float c, float d) {
    float t  = 0.04f * v * v + 5.0f * v + 140.0f - u + I;
    float v_ = v + 0.25f * t;
    float u_ = u + 0.005f * (b * v - u);
    float z  = (v_ >= 30.0f) ? 1.0f : 0.0f;
    v = (v_ >= 30.0f) ? c : v_;
    u = u_ + z * d;
    return z;
}

// ---------------------------------------------------------------------------
// Kernel 2: ONE CHANNEL per thread. The two channels of a batch element are
// fully independent given Ssum, so splitting them halves the per-thread
// serial dependency chain (the measured bottleneck: ~830 cyc/step with both
// channels in one thread, VALU ~60% busy on its single SIMD).
// Grid = 64 blocks x 64 threads: blocks [0,32) = channel 1, [32,64) = ch 2.
// Control flow is block-uniform (no divergence).
// ---------------------------------------------------------------------------
__global__ __launch_bounds__(64) void scan_ch_kernel(const float* __restrict__ S,
                                                     const float* __restrict__ w24,
                                                     float* __restrict__ out) {
    const int lane = threadIdx.x;
    const int ch   = (blockIdx.x >= 32) ? 1 : 0;
    const int b    = (blockIdx.x & 31) * 64 + lane;

    // per-channel weight selection (uniform per block)
    const float a0  = ch ? w24[12] : w24[0];   // Ssum -> zp
    const float a1  = ch ? w24[13] : w24[1];
    const float w2c = w24[2],  w3c = w24[3];
    const float a4  = ch ? w24[16] : w24[4];
    const float a5  = ch ? w24[17] : w24[5];
    const float a6  = ch ? w24[18] : w24[6];
    const float a8  = ch ? w24[20] : w24[8];
    const float w9c = w24[9],  w10c = w24[10];
    const float a11 = ch ? w24[23] : w24[11];

    float vL = -70.f, uL = -14.f, zL = 0.f;
    float vE = -64.f, uE = -16.f;
    float vI = -64.f, uI = -16.f;
    float vT = -70.f, uT = -14.f, zT = 0.f;
    float vM = -64.f, uM = -16.f;

    const float4* Srow = (const float4*)(S + (size_t)b * T_);
    // scalar outputs: ch0 -> (o_spikes, v); ch1 -> (o_spikes2, v2)
    float4* q0 = (float4*)(out + ((size_t)(ch ? 2 : 0) * BT) + (size_t)b * T_);
    float4* q1 = (float4*)(out + ((size_t)(ch ? 3 : 1) * BT) + (size_t)b * T_);
    // x4 outputs (channel 1 only)
    float4* p4 = (float4*)out + (size_t)BT + (size_t)b * T_;      // o_spikes_o
    float4* p5 = (float4*)out + (size_t)2 * BT + (size_t)b * T_;  // v_o

    float4 sc = Srow[0];
    float4 sn = Srow[1];
    for (int i = 0; i < T_ / 4; ++i) {
        float4 sn2 = sn;
        if (i + 2 < T_ / 4) sn2 = Srow[i + 2];
        float sv[4] = {sc.x, sc.y, sc.z, sc.w};
        float o0[4], o1[4];
#pragma unroll
        for (int k = 0; k < 4; ++k) {
            const int t = 4 * i + k;
            const float zp = sv[k] * a0;
            float z2 = izh(vL, uL, w2c * (zp * a1) + w3c * zL,  0.20f, -65.f, 6.f);
            float z3 = izh(vE, uE, zp * a4 + z2 * a5,           0.25f, -55.f, 0.05f);
            float z4 = izh(vI, uI, z3 * a6,                     0.25f, -65.f, 6.f);
            float z5 = izh(vT, uT, w9c * (z3 * a8) + w10c * zT, 0.20f, -50.f, 2.f);
            float z6 = izh(vM, uM, z5 * a11,                    0.25f, -65.f, 6.f);
            zL = z2; zT = z5;
            o0[k] = z6; o1[k] = vM;
            if (ch == 0) {
                p4[t] = make_float4(z2, z3, z4, z5);
                p5[t] = make_float4(vL, vE, vI, vT);
            }
        }
        q0[i] = make_float4(o0[0], o0[1], o0[2], o0[3]);
        q1[i] = make_float4(o1[0], o1[1], o1[2], o1[3]);
        sc = sn;
        sn = sn2;
    }
}

// ---------------------------------------------------------------------------
// Fallback (tiny ws): both channels in one thread, S aliasing out's o_spikes
// region (per-thread reads strictly lead writes; no restrict -> order kept).
// ---------------------------------------------------------------------------
__global__ __launch_bounds__(64) void scan_kernel_alias(const float* S,
                                                        const float* __restrict__ w24,
                                                        float* out) {
    int b = blockIdx.x * 64 + threadIdx.x;
    if (b >= B_) return;

    const float w0 = w24[0],  w1 = w24[1],  w2 = w24[2],  w3 = w24[3];
    const float w4 = w24[4],  w5 = w24[5],  w6 = w24[6];
    const float w8 = w24[8],  w9 = w24[9],  w10 = w24[10], w11 = w24[11];
    const float w12 = w24[12], w13 = w24[13], w16 = w24[16], w17 = w24[17];
    const float w18 = w24[18], w20 = w24[20], w23 = w24[23];

    float vL = -70.f, uL = -14.f, zL = 0.f;
    float vE = -64.f, uE = -16.f;
    float vI = -64.f, uI = -16.f;
    float vT = -70.f, uT = -14.f, zT = 0.f;
    float vM = -64.f, uM = -16.f;
    float vL2 = -70.f, uL2 = -14.f, zL2 = 0.f;
    float vE2 = -64.f, uE2 = -16.f;
    float vI2 = -64.f, uI2 = -16.f;
    float vT2 = -70.f, uT2 = -14.f, zT2 = 0.f;
    float vM2 = -64.f, uM2 = -16.f;

    const float4* Srow = (const float4*)(S + (size_t)b * T_);
    float* p0 = out + (size_t)b * T_;
    float* p1 = p0 + (size_t)BT;
    float* p2 = p0 + (size_t)2 * BT;
    float* p3 = p0 + (size_t)3 * BT;
    float4* p4 = (float4*)out + (size_t)BT + (size_t)b * T_;
    float4* p5 = (float4*)out + (size_t)2 * BT + (size_t)b * T_;

    float4 sc = Srow[0];
    for (int i = 0; i < T_ / 4; ++i) {
        float4 sn = sc;
        if (i + 1 < T_ / 4) sn = Srow[i + 1];
        float sv[4] = {sc.x, sc.y, sc.z, sc.w};
#pragma unroll
        for (int k = 0; k < 4; ++k) {
            int t = 4 * i + k;
            float Ssum = sv[k];
            float zp  = Ssum * w0;
            float zp2 = Ssum * w12;
            float z2 = izh(vL, uL, w2 * (zp * w1) + w3 * zL, 0.20f, -65.f, 6.f);
            float z3 = izh(vE, uE, zp * w4 + z2 * w5,        0.25f, -55.f, 0.05f);
            float z4 = izh(vI, uI, z3 * w6,                  0.25f, -65.f, 6.f);
            float z5 = izh(vT, uT, w9 * (z3 * w8) + w10 * zT,0.20f, -50.f, 2.f);
            float z6 = izh(vM, uM, z5 * w11,                 0.25f, -65.f, 6.f);
            zL = z2; zT = z5;
            float z22 = izh(vL2, uL2, w2 * (zp2 * w13) + w3 * zL2, 0.20f, -65.f, 6.f);
            float z32 = izh(vE2, uE2, zp2 * w16 + z22 * w17,       0.25f, -55.f, 0.05f);
            float z42 = izh(vI2, uI2, z32 * w18,                   0.25f, -65.f, 6.f);
            float z52 = izh(vT2, uT2, w9 * (z32 * w20) + w10 * zT2,0.20f, -50.f, 2.f);
            float z62 = izh(vM2, uM2, z52 * w23,                   0.25f, -65.f, 6.f);
            zL2 = z22; zT2 = z52;
            (void)z42;

            p0[t] = z6;
            p1[t] = vM;
            p2[t] = z62;
            p3[t] = vM2;
            p4[t] = make_float4(z2, z3, z4, z5);
            p5[t] = make_float4(vL, vE, vI, vT);
        }
        sc = sn;
    }
}

extern "C" void kernel_launch(void* const* d_in, const int* in_sizes, int n_in,
                              void* d_out, int out_size, void* d_ws, size_t ws_size,
                              hipStream_t stream) {
    const float* in = (const float*)d_in[0];
    const float* w  = (const float*)d_in[1];
    float* out = (float*)d_out;

    bool use_ws = ws_size >= (size_t)BT * sizeof(float);
    float* S = use_ws ? (float*)d_ws : out;

    rowsum_kernel<<<(BT * 16) / 256, 256, 0, stream>>>(in, S);

    if (use_ws) {
        // 64 blocks: [0,32) = channel 1, [32,64) = channel 2.
        scan_ch_kernel<<<64, 64, 0, stream>>>(S, w, out);
    } else {
        scan_kernel_alias<<<(B_ + 63) / 64, 64, 0, stream>>>(S, w, out);
    }
}

// Round 5
// 158.333 us; speedup vs baseline: 1.4111x; 1.1241x over previous
//
#include <hip/hip_runtime.h>

#define B_ 2048
#define T_ 500
#define N_ 64
#define BT (B_ * T_)

// ---------------------------------------------------------------------------
// Kernel 1: row sums.  S[r] = sum_n input[r*64 + n],  r = b*T + t.
// 16 lanes cooperate per row; fully coalesced 1 KB/wave loads. HBM roofline.
// ---------------------------------------------------------------------------
__global__ __launch_bounds__(256) void rowsum_kernel(const float* __restrict__ in,
                                                     float* __restrict__ S) {
    long long gid = (long long)blockIdx.x * 256 + threadIdx.x;  // chunk index
    const float4* p = (const float4*)in;
    float4 v = p[gid];
    float s = (v.x + v.y) + (v.z + v.w);
    s += __shfl_xor(s, 1);
    s += __shfl_xor(s, 2);
    s += __shfl_xor(s, 4);
    s += __shfl_xor(s, 8);
    if ((threadIdx.x & 15) == 0) S[gid >> 4] = s;
}

// ---------------------------------------------------------------------------
// Izhikevich Euler step — association order matches the reference exactly.
// DT = 0.25; all neuron types have a = 0.02 -> DT*a = 0.005f.
// ---------------------------------------------------------------------------
__device__ __forceinline__ float izh(float& v, float& u, float I,
                                     float b, float c, float d) {
    float t  = 0.04f * v * v + 5.0f * v + 140.0f - u + I;
    float v_ = v + 0.25f * t;
    float u_ = u + 0.005f * (b * v - u);
    float z  = (v_ >= 30.0f) ? 1.0f : 0.0f;
    v = (v_ >= 30.0f) ? c : v_;
    u = u_ + z * d;
    return z;
}

// ---------------------------------------------------------------------------
// Kernel 2: one channel per thread, neurons SOFTWARE-PIPELINED across time:
// at iteration j we compute L(step j), E(j-1), I(j-2), T(j-2), M(j-3).
// All inter-neuron deps come from previous-iteration registers, so the 5 izh
// chains inside one iteration are independent -> ILP hides dep latency; the
// wave becomes instruction-issue bound (~180 cyc/step) instead of
// chain-latency bound (~620 cyc/step).
// Histories at START of iter j:
//   zL   = z2(j-1)   (used by L self-feedback AND E same-step input)
//   z3h  = z3(j-2)   (used by I and T, and the o_spikes_o store)
//   z5h  = z5(j-3)   (used by T self-feedback and M same-step input)
//   z2h2 = z2(j-2), zph = zp(j-1), vLh = vL(j-2)  (stores)
// Grid = 64 blocks x 64 threads: blocks [0,32) = channel 1, [32,64) = ch 2.
// ---------------------------------------------------------------------------
__global__ __launch_bounds__(64) void scan_pipe_kernel(const float* __restrict__ S,
                                                       const float* __restrict__ w24,
                                                       float* __restrict__ out) {
    const int lane = threadIdx.x;
    const int ch   = (blockIdx.x >= 32) ? 1 : 0;
    const int b    = (blockIdx.x & 31) * 64 + lane;

    const float a0  = ch ? w24[12] : w24[0];
    const float a1  = ch ? w24[13] : w24[1];
    const float w2c = w24[2],  w3c = w24[3];
    const float a4  = ch ? w24[16] : w24[4];
    const float a5  = ch ? w24[17] : w24[5];
    const float a6  = ch ? w24[18] : w24[6];
    const float a8  = ch ? w24[20] : w24[8];
    const float w9c = w24[9],  w10c = w24[10];
    const float a11 = ch ? w24[23] : w24[11];

    float vL = -70.f, uL = -14.f;
    float vE = -64.f, uE = -16.f;
    float vI = -64.f, uI = -16.f;
    float vT = -70.f, uT = -14.f;
    float vM = -64.f, uM = -16.f;
    float zL = 0.f, z3h = 0.f, z5h = 0.f, z2h2 = 0.f, zph = 0.f, vLh = -70.f;

    const float4* S4 = (const float4*)(S + (size_t)b * T_);
    float* q0 = out + (size_t)(ch ? 2 : 0) * BT + (size_t)b * T_;  // o_spikes(2)
    float* q1 = out + (size_t)(ch ? 3 : 1) * BT + (size_t)b * T_;  // v(2)
    float4* p4 = (float4*)out + (size_t)BT + (size_t)b * T_;       // o_spikes_o
    float4* p5 = (float4*)out + (size_t)2 * BT + (size_t)b * T_;   // v_o

    // ---------------- warm-up: j = 0..3 ----------------
    float4 s0 = S4[0];
    {   // j=0: L(0)
        float zpc = s0.x * a0;
        float zLs = zL, vLp = vL;
        float z2n = izh(vL, uL, w2c * (zpc * a1) + w3c * zLs, 0.20f, -65.f, 6.f);
        z2h2 = zLs; zL = z2n; zph = zpc; vLh = vLp;
    }
    {   // j=1: L(1), E(0)
        float zpc = s0.y * a0;
        float zLs = zL, vLp = vL;
        float z2n = izh(vL, uL, w2c * (zpc * a1) + w3c * zLs, 0.20f, -65.f, 6.f);
        float z3n = izh(vE, uE, zph * a4 + zLs * a5,          0.25f, -55.f, 0.05f);
        z2h2 = zLs; zL = z2n; z3h = z3n; zph = zpc; vLh = vLp;
    }
    {   // j=2: L(2), E(1), I(0), T(0); store o_spikes_o[0], v_o[0]
        float zpc = s0.z * a0;
        float zLs = zL, vLp = vL, vEp = vE;
        float z2n = izh(vL, uL, w2c * (zpc * a1) + w3c * zLs,   0.20f, -65.f, 6.f);
        float z3n = izh(vE, uE, zph * a4 + zLs * a5,            0.25f, -55.f, 0.05f);
        float z4n = izh(vI, uI, z3h * a6,                       0.25f, -65.f, 6.f);
        float z5n = izh(vT, uT, w9c * (z3h * a8) + w10c * z5h,  0.20f, -50.f, 2.f);
        if (ch == 0) {
            p4[0] = make_float4(z2h2, z3h, z4n, z5n);
            p5[0] = make_float4(vLh, vEp, vI, vT);
        }
        z2h2 = zLs; zL = z2n; z3h = z3n; z5h = z5n; zph = zpc; vLh = vLp;
    }
    {   // j=3: full; stores t=1 (x4) and t=0 (scalar)
        float zpc = s0.w * a0;
        float zLs = zL, vLp = vL, vEp = vE;
        float z2n = izh(vL, uL, w2c * (zpc * a1) + w3c * zLs,   0.20f, -65.f, 6.f);
        float z3n = izh(vE, uE, zph * a4 + zLs * a5,            0.25f, -55.f, 0.05f);
        float z4n = izh(vI, uI, z3h * a6,                       0.25f, -65.f, 6.f);
        float z5n = izh(vT, uT, w9c * (z3h * a8) + w10c * z5h,  0.20f, -50.f, 2.f);
        float z6n = izh(vM, uM, z5h * a11,                      0.25f, -65.f, 6.f);
        q0[0] = z6n; q1[0] = vM;
        if (ch == 0) {
            p4[1] = make_float4(z2h2, z3h, z4n, z5n);
            p5[1] = make_float4(vLh, vEp, vI, vT);
        }
        z2h2 = zLs; zL = z2n; z3h = z3n; z5h = z5n; zph = zpc; vLh = vLp;
    }

    // ---------------- main loop: j = 4..499 (124 groups of 4) ----------------
    float4 cur = S4[1];
    float4 nxt = S4[2];
    for (int g = 0; g < 124; ++g) {
        float4 nn = nxt;
        if (g + 3 <= 124) nn = S4[g + 3];  // 2-group-deep prefetch
        float svv[4] = {cur.x, cur.y, cur.z, cur.w};
#pragma unroll
        for (int k = 0; k < 4; ++k) {
            const int j = 4 * g + 4 + k;
            float zpc = svv[k] * a0;
            float zLs = zL, vLp = vL, vEp = vE;
            float z2n = izh(vL, uL, w2c * (zpc * a1) + w3c * zLs,   0.20f, -65.f, 6.f);
            float z3n = izh(vE, uE, zph * a4 + zLs * a5,            0.25f, -55.f, 0.05f);
            float z4n = izh(vI, uI, z3h * a6,                       0.25f, -65.f, 6.f);
            float z5n = izh(vT, uT, w9c * (z3h * a8) + w10c * z5h,  0.20f, -50.f, 2.f);
            float z6n = izh(vM, uM, z5h * a11,                      0.25f, -65.f, 6.f);
            q0[j - 3] = z6n;
            q1[j - 3] = vM;
            if (ch == 0) {
                p4[j - 2] = make_float4(z2h2, z3h, z4n, z5n);
                p5[j - 2] = make_float4(vLh, vEp, vI, vT);
            }
            z2h2 = zLs; zL = z2n; z3h = z3n; z5h = z5n; zph = zpc; vLh = vLp;
        }
        cur = nxt; nxt = nn;
    }

    // ---------------- drain: j = 500, 501, 502 ----------------
    {   // j=500: E(499), I(498), T(498), M(497)
        float zLs = zL, vLp = vL, vEp = vE;
        float z3n = izh(vE, uE, zph * a4 + zLs * a5,            0.25f, -55.f, 0.05f);
        float z4n = izh(vI, uI, z3h * a6,                       0.25f, -65.f, 6.f);
        float z5n = izh(vT, uT, w9c * (z3h * a8) + w10c * z5h,  0.20f, -50.f, 2.f);
        float z6n = izh(vM, uM, z5h * a11,                      0.25f, -65.f, 6.f);
        q0[497] = z6n; q1[497] = vM;
        if (ch == 0) {
            p4[498] = make_float4(z2h2, z3h, z4n, z5n);
            p5[498] = make_float4(vLh, vEp, vI, vT);
        }
        z2h2 = zLs; z3h = z3n; z5h = z5n; vLh = vLp;
    }
    {   // j=501: I(499), T(499), M(498)
        float vEp = vE;
        float z4n = izh(vI, uI, z3h * a6,                       0.25f, -65.f, 6.f);
        float z5n = izh(vT, uT, w9c * (z3h * a8) + w10c * z5h,  0.20f, -50.f, 2.f);
        float z6n = izh(vM, uM, z5h * a11,                      0.25f, -65.f, 6.f);
        q0[498] = z6n; q1[498] = vM;
        if (ch == 0) {
            p4[499] = make_float4(z2h2, z3h, z4n, z5n);
            p5[499] = make_float4(vLh, vEp, vI, vT);
        }
        z5h = z5n;
    }
    {   // j=502: M(499)
        float z6n = izh(vM, uM, z5h * a11,                      0.25f, -65.f, 6.f);
        q0[499] = z6n; q1[499] = vM;
    }
}

// ---------------------------------------------------------------------------
// Fallback (tiny ws): both channels in one thread, S aliasing out's o_spikes
// region (per-thread reads strictly lead writes; no restrict -> order kept).
// ---------------------------------------------------------------------------
__global__ __launch_bounds__(64) void scan_kernel_alias(const float* S,
                                                        const float* __restrict__ w24,
                                                        float* out) {
    int b = blockIdx.x * 64 + threadIdx.x;
    if (b >= B_) return;

    const float w0 = w24[0],  w1 = w24[1],  w2 = w24[2],  w3 = w24[3];
    const float w4 = w24[4],  w5 = w24[5],  w6 = w24[6];
    const float w8 = w24[8],  w9 = w24[9],  w10 = w24[10], w11 = w24[11];
    const float w12 = w24[12], w13 = w24[13], w16 = w24[16], w17 = w24[17];
    const float w18 = w24[18], w20 = w24[20], w23 = w24[23];

    float vL = -70.f, uL = -14.f, zL = 0.f;
    float vE = -64.f, uE = -16.f;
    float vI = -64.f, uI = -16.f;
    float vT = -70.f, uT = -14.f, zT = 0.f;
    float vM = -64.f, uM = -16.f;
    float vL2 = -70.f, uL2 = -14.f, zL2 = 0.f;
    float vE2 = -64.f, uE2 = -16.f;
    float vI2 = -64.f, uI2 = -16.f;
    float vT2 = -70.f, uT2 = -14.f, zT2 = 0.f;
    float vM2 = -64.f, uM2 = -16.f;

    const float4* Srow = (const float4*)(S + (size_t)b * T_);
    float* p0 = out + (size_t)b * T_;
    float* p1 = p0 + (size_t)BT;
    float* p2 = p0 + (size_t)2 * BT;
    float* p3 = p0 + (size_t)3 * BT;
    float4* p4 = (float4*)out + (size_t)BT + (size_t)b * T_;
    float4* p5 = (float4*)out + (size_t)2 * BT + (size_t)b * T_;

    float4 sc = Srow[0];
    for (int i = 0; i < T_ / 4; ++i) {
        float4 sn = sc;
        if (i + 1 < T_ / 4) sn = Srow[i + 1];
        float sv[4] = {sc.x, sc.y, sc.z, sc.w};
#pragma unroll
        for (int k = 0; k < 4; ++k) {
            int t = 4 * i + k;
            float Ssum = sv[k];
            float zp  = Ssum * w0;
            float zp2 = Ssum * w12;
            float z2 = izh(vL, uL, w2 * (zp * w1) + w3 * zL, 0.20f, -65.f, 6.f);
            float z3 = izh(vE, uE, zp * w4 + z2 * w5,        0.25f, -55.f, 0.05f);
            float z4 = izh(vI, uI, z3 * w6,                  0.25f, -65.f, 6.f);
            float z5 = izh(vT, uT, w9 * (z3 * w8) + w10 * zT,0.20f, -50.f, 2.f);
            float z6 = izh(vM, uM, z5 * w11,                 0.25f, -65.f, 6.f);
            zL = z2; zT = z5;
            float z22 = izh(vL2, uL2, w2 * (zp2 * w13) + w3 * zL2, 0.20f, -65.f, 6.f);
            float z32 = izh(vE2, uE2, zp2 * w16 + z22 * w17,       0.25f, -55.f, 0.05f);
            float z42 = izh(vI2, uI2, z32 * w18,                   0.25f, -65.f, 6.f);
            float z52 = izh(vT2, uT2, w9 * (z32 * w20) + w10 * zT2,0.20f, -50.f, 2.f);
            float z62 = izh(vM2, uM2, z52 * w23,                   0.25f, -65.f, 6.f);
            zL2 = z22; zT2 = z52;
            (void)z42;

            p0[t] = z6;
            p1[t] = vM;
            p2[t] = z62;
            p3[t] = vM2;
            p4[t] = make_float4(z2, z3, z4, z5);
            p5[t] = make_float4(vL, vE, vI, vT);
        }
        sc = sn;
    }
}

extern "C" void kernel_launch(void* const* d_in, const int* in_sizes, int n_in,
                              void* d_out, int out_size, void* d_ws, size_t ws_size,
                              hipStream_t stream) {
    const float* in = (const float*)d_in[0];
    const float* w  = (const float*)d_in[1];
    float* out = (float*)d_out;

    bool use_ws = ws_size >= (size_t)BT * sizeof(float);
    float* S = use_ws ? (float*)d_ws : out;

    rowsum_kernel<<<(BT * 16) / 256, 256, 0, stream>>>(in, S);

    if (use_ws) {
        // 64 blocks: [0,32) = channel 1, [32,64) = channel 2.
        scan_pipe_kernel<<<64, 64, 0, stream>>>(S, w, out);
    } else {
        scan_kernel_alias<<<(B_ + 63) / 64, 64, 0, stream>>>(S, w, out);
    }
}